// Round 10
// baseline (109.978 us; speedup 1.0000x reference)
//
#include <hip/hip_runtime.h>
#include <hip/hip_fp16.h>

// Problem constants (match reference)
constexpr int B = 128;
constexpr int N = 16384;
constexpr int H = 512;
constexpr int W = 512;
constexpr int HW = H * W;                        // 262144
constexpr long long TOT = (long long)B * HW;     // 33554432 pixels

constexpr int TROWS = 8;                         // rows per tile (small => 8 blocks/CU)
constexpr int NTILES = H / TROWS;                // 64 tiles per frame
constexpr int NBUCKETS = B * NTILES;             // 8192
constexpr int CAP = 512;                         // slots per bucket (mean ~290)
constexpr int NGROUPS = B * N / 4;               // 524288 groups of 4 points
constexpr int BIN_BLOCKS = NGROUPS / 512;        // 1024
constexpr int TPITCH = 520;                      // padded pitch (bank spread)
constexpr int TILE_WORDS = TROWS * TPITCH;       // 4160 floats = 16640 B
constexpr int MSE_BLOCKS = 2048;

__device__ __forceinline__ void lds_add(float* p, float v) {
    __hip_atomic_fetch_add(p, v, __ATOMIC_RELAXED, __HIP_MEMORY_SCOPE_WORKGROUP);
}

__device__ __forceinline__ unsigned pack2(float a, float b) {
    __half2 h = __floats2half2_rn(a, b);
    return *reinterpret_cast<unsigned*>(&h);
}

__device__ __forceinline__ float2 unpack2(unsigned u) {
    __half2 h = *reinterpret_cast<__half2*>(&u);
    return __half22float2(h);
}

// ---------------------------------------------------------------------------
// Kernel 0: zero the 8192 bucket counters
// ---------------------------------------------------------------------------
__global__ void __launch_bounds__(512) k_zero(unsigned int* __restrict__ cnt) {
    cnt[blockIdx.x * 512 + threadIdx.x] = 0u;
}

// ---------------------------------------------------------------------------
// Kernel 1: bin points by (frame, 8-row tile), per-block LDS slot aggregation.
// ---------------------------------------------------------------------------
__global__ void __launch_bounds__(512) k_bin(const float4* __restrict__ pts,
                                             float4* __restrict__ buckets,
                                             unsigned int* __restrict__ cnt) {
    __shared__ unsigned int lcnt[NTILES];
    __shared__ unsigned int lbase[NTILES];

    int tid = blockIdx.x * 512 + threadIdx.x;    // one group of 4 points
    int frame = tid >> 12;                       // 4096 groups per frame
    int fb = frame * NTILES;

    if (threadIdx.x < NTILES) lcnt[threadIdx.x] = 0;
    __syncthreads();

    float4 a = pts[tid * 3 + 0];   // x0 y0 i0 x1
    float4 b = pts[tid * 3 + 1];   // y1 i1 x2 y2
    float4 c = pts[tid * 3 + 2];   // i2 x3 y3 i3

    float xs[4] = {a.x, a.w, b.z, c.y};
    float ys[4] = {a.y, b.x, b.w, c.z};
    float is[4] = {a.z, b.y, c.x, c.w};

    int tb0[4], sl0[4], tb1[4], sl1[4];
#pragma unroll
    for (int k = 0; k < 4; ++k) {
        float x = fminf(fmaxf(xs[k], 0.0f), (float)(W - 1));
        float y = fminf(fmaxf(ys[k], 0.0f), (float)(H - 1));
        xs[k] = x; ys[k] = y;
        int y0 = (int)floorf(y);
        int y1 = min(y0 + 1, H - 1);
        int t0 = y0 >> 3;                         // TROWS = 8
        int t1 = y1 >> 3;
        tb0[k] = t0;
        sl0[k] = (int)atomicAdd(&lcnt[t0], 1u);
        if (t1 != t0) {
            tb1[k] = t1;
            sl1[k] = (int)atomicAdd(&lcnt[t1], 1u);
        } else {
            tb1[k] = -1; sl1[k] = 0;
        }
    }
    __syncthreads();

    if (threadIdx.x < NTILES)
        lbase[threadIdx.x] = atomicAdd(&cnt[fb + threadIdx.x], lcnt[threadIdx.x]);
    __syncthreads();

#pragma unroll
    for (int k = 0; k < 4; ++k) {
        float4 rec = make_float4(xs[k], ys[k], is[k], 0.0f);
        unsigned s0 = lbase[tb0[k]] + (unsigned)sl0[k];
        if (s0 < (unsigned)CAP)
            buckets[(size_t)(fb + tb0[k]) * CAP + s0] = rec;
        if (tb1[k] >= 0) {
            unsigned s1 = lbase[tb1[k]] + (unsigned)sl1[k];
            if (s1 < (unsigned)CAP)
                buckets[(size_t)(fb + tb1[k]) * CAP + s1] = rec;
        }
    }
}

// ---------------------------------------------------------------------------
// Kernel 2: per-(frame,tile) block: zero 16.6KB LDS tile, splat own bucket
// (ds_add), convert to fp16 and store tile to global img. No target read,
// no reduce. 256 threads, 8 blocks/CU concurrent.
// ---------------------------------------------------------------------------
__global__ void __launch_bounds__(256) k_splat(const float4* __restrict__ buckets,
                                               const unsigned int* __restrict__ cnt,
                                               unsigned* __restrict__ img_u) {
    __shared__ __align__(16) float tile[TILE_WORDS];
    int bid = blockIdx.x;
    int frame = bid >> 6;                        // NTILES = 64
    int t = bid & (NTILES - 1);
    int r0 = t * TROWS;
    int tid = threadIdx.x;

    // zero tile: 1040 float4 over 256 threads
    float4* t4 = (float4*)tile;
    float4 z = make_float4(0.f, 0.f, 0.f, 0.f);
    for (int i = tid; i < TILE_WORDS / 4; i += 256)
        t4[i] = z;
    int n = (int)min(cnt[bid], (unsigned)CAP);
    __syncthreads();

    const float4* bp = buckets + (size_t)bid * CAP;
    for (int i = tid; i < n; i += 256) {
        float4 p = bp[i];
        float x = p.x, y = p.y, inten = p.z;     // clamped at bin time
        float x0f = floorf(x), y0f = floorf(y);
        float fx = x - x0f, fy = y - y0f;
        int x0 = (int)x0f, y0 = (int)y0f;
        int x1 = min(x0 + 1, W - 1);
        int y1 = min(y0 + 1, H - 1);
        int ra = y0 - r0;
        int rb = y1 - r0;
        float w00 = inten * (1.0f - fx) * (1.0f - fy);
        float w01 = inten * fx * (1.0f - fy);
        float w10 = inten * (1.0f - fx) * fy;
        float w11 = inten * fx * fy;
        if ((unsigned)ra < (unsigned)TROWS) {
            lds_add(&tile[ra * TPITCH + x0], w00);
            lds_add(&tile[ra * TPITCH + x1], w01);
        }
        if ((unsigned)rb < (unsigned)TROWS) {
            lds_add(&tile[rb * TPITCH + x0], w10);
            lds_add(&tile[rb * TPITCH + x1], w11);
        }
    }
    __syncthreads();

    // convert + store: thread owns 16 consecutive pixels (tid*16)
    int g = tid * 16;
    int r = g >> 9;                              // row in tile
    int c = g & 511;                             // col
    const float* src = &tile[r * TPITCH + c];
    unsigned ou[8];
#pragma unroll
    for (int k = 0; k < 4; ++k) {
        float4 v = *(const float4*)(src + k * 4);
        ou[2 * k]     = pack2(v.x, v.y);
        ou[2 * k + 1] = pack2(v.z, v.w);
    }
    // img halfs base: frame*HW + r0*W ; uint index = that/2
    size_t ubase = ((size_t)frame * HW + (size_t)r0 * W) >> 1;
    uint4* dst = (uint4*)(img_u + ubase);        // 8 halfs per uint4
    dst[tid * 2]     = make_uint4(ou[0], ou[1], ou[2], ou[3]);
    dst[tid * 2 + 1] = make_uint4(ou[4], ou[5], ou[6], ou[7]);
}

// ---------------------------------------------------------------------------
// Kernel 3: streaming MSE: sum (img_fp16 - tgt)^2 over all pixels.
// Long grid-stride loop; 8 pixels per iteration per thread.
// ---------------------------------------------------------------------------
__global__ void __launch_bounds__(256) k_mse(const uint4* __restrict__ img_u4,
                                             const float4* __restrict__ tgt4,
                                             double* __restrict__ pmse) {
    int tid0 = blockIdx.x * 256 + threadIdx.x;
    int nthr = MSE_BLOCKS * 256;
    int units = (int)(TOT / 8);                  // 4194304
    double acc = 0.0;
    for (int i = tid0; i < units; i += nthr) {
        uint4 iu = img_u4[i];                    // 8 halfs
        float4 ta = tgt4[2 * i];
        float4 tb = tgt4[2 * i + 1];
        float2 i0 = unpack2(iu.x);
        float2 i1 = unpack2(iu.y);
        float2 i2 = unpack2(iu.z);
        float2 i3 = unpack2(iu.w);
        float d0 = i0.x - ta.x, d1 = i0.y - ta.y;
        float d2 = i1.x - ta.z, d3 = i1.y - ta.w;
        float d4 = i2.x - tb.x, d5 = i2.y - tb.y;
        float d6 = i3.x - tb.z, d7 = i3.y - tb.w;
        float s = d0 * d0 + d1 * d1 + d2 * d2 + d3 * d3 +
                  d4 * d4 + d5 * d5 + d6 * d6 + d7 * d7;
        acc += (double)s;
    }
    for (int off = 32; off > 0; off >>= 1)
        acc += __shfl_down(acc, off, 64);
    __shared__ double sacc[4];
    int lane = threadIdx.x & 63;
    int wave = threadIdx.x >> 6;
    if (lane == 0) sacc[wave] = acc;
    __syncthreads();
    if (threadIdx.x == 0)
        pmse[blockIdx.x] = sacc[0] + sacc[1] + sacc[2] + sacc[3];
}

// ---------------------------------------------------------------------------
// Kernel 4: final reduce of MSE_BLOCKS partials -> mean -> d_out[0]
// ---------------------------------------------------------------------------
__global__ void __launch_bounds__(512) k_final(const double* __restrict__ pmse,
                                               float* __restrict__ out) {
    double acc = 0.0;
    for (int i = threadIdx.x; i < MSE_BLOCKS; i += 512)
        acc += pmse[i];
    for (int off = 32; off > 0; off >>= 1)
        acc += __shfl_down(acc, off, 64);
    __shared__ double sacc[8];
    int lane = threadIdx.x & 63;
    int wave = threadIdx.x >> 6;
    if (lane == 0) sacc[wave] = acc;
    __syncthreads();
    if (threadIdx.x == 0) {
        double s = 0.0;
#pragma unroll
        for (int wv = 0; wv < 8; ++wv) s += sacc[wv];
        out[0] = (float)(s / (double)TOT);
    }
}

// ---------------------------------------------------------------------------
extern "C" void kernel_launch(void* const* d_in, const int* in_sizes, int n_in,
                              void* d_out, int out_size, void* d_ws, size_t ws_size,
                              hipStream_t stream) {
    const float* pts = (const float*)d_in[0];     // [B, N, 3]
    const float* tgt = (const float*)d_in[1];     // [B, H, W]
    float* out = (float*)d_out;

    // ws layout: [cnt 32KB | pmse 16KB | pad to 128KB | buckets 64MiB | img 64MiB]
    unsigned int* cnt = (unsigned int*)d_ws;
    double* pmse = (double*)((char*)d_ws + 32768);
    float4* buckets = (float4*)((char*)d_ws + 131072);
    unsigned* img_u = (unsigned*)((char*)d_ws + 131072 + ((size_t)NBUCKETS * CAP * 16));

    k_zero<<<NBUCKETS / 512, 512, 0, stream>>>(cnt);
    k_bin<<<BIN_BLOCKS, 512, 0, stream>>>((const float4*)pts, buckets, cnt);
    k_splat<<<NBUCKETS, 256, 0, stream>>>(buckets, cnt, img_u);
    k_mse<<<MSE_BLOCKS, 256, 0, stream>>>((const uint4*)img_u, (const float4*)tgt, pmse);
    k_final<<<1, 512, 0, stream>>>(pmse, out);
}

// Round 11
// 94.632 us; speedup vs baseline: 1.1622x; 1.1622x over previous
//
#include <hip/hip_runtime.h>

// Problem constants (match reference)
constexpr int B = 128;
constexpr int N = 16384;
constexpr int H = 512;
constexpr int W = 512;
constexpr int HW = H * W;                        // 262144
constexpr long long TOT = (long long)B * HW;     // 33554432 pixels

constexpr int TROWS = 8;                         // rows per tile
constexpr int NTILES = H / TROWS;                // 64 tiles per frame
constexpr int NBUCKETS = B * NTILES;             // 8192
constexpr int CAP = 512;                         // slots/bucket (mean ~288, 13 sigma)
constexpr int NGROUPS = B * N / 4;               // 524288 groups of 4 points
constexpr int BIN_BLOCKS = NGROUPS / 512;        // 1024
constexpr int TPITCH = 520;                      // padded accumulator pitch
constexpr int TILE_WORDS = TROWS * TPITCH;       // 4160 floats = 16640 B
constexpr int TPB = 16;                          // tiles per persistent block
constexpr int TILE_BLOCKS = NBUCKETS / TPB;      // 512 blocks (2/CU by LDS)

__device__ __forceinline__ void lds_add(float* p, float v) {
    __hip_atomic_fetch_add(p, v, __ATOMIC_RELAXED, __HIP_MEMORY_SCOPE_WORKGROUP);
}

// async global->LDS, 16B per lane; side-effecting intrinsic: CANNOT be sunk
__device__ __forceinline__ void gload16(const void* g, void* s) {
    __builtin_amdgcn_global_load_lds(
        (const __attribute__((address_space(1))) void*)g,
        (__attribute__((address_space(3))) void*)s,
        16, 0, 0);
}

// ---------------------------------------------------------------------------
// Kernel 0: zero the 8192 bucket counters
// ---------------------------------------------------------------------------
__global__ void __launch_bounds__(512) k_zero(unsigned int* __restrict__ cnt) {
    cnt[blockIdx.x * 512 + threadIdx.x] = 0u;
}

// ---------------------------------------------------------------------------
// Kernel 1: bin points by (frame, 8-row tile), per-block LDS slot aggregation.
// ---------------------------------------------------------------------------
__global__ void __launch_bounds__(512) k_bin(const float4* __restrict__ pts,
                                             float4* __restrict__ buckets,
                                             unsigned int* __restrict__ cnt) {
    __shared__ unsigned int lcnt[NTILES];
    __shared__ unsigned int lbase[NTILES];

    int tid = blockIdx.x * 512 + threadIdx.x;    // one group of 4 points
    int frame = tid >> 12;                       // 4096 groups per frame
    int fb = frame * NTILES;

    if (threadIdx.x < NTILES) lcnt[threadIdx.x] = 0;
    __syncthreads();

    float4 a = pts[tid * 3 + 0];   // x0 y0 i0 x1
    float4 b = pts[tid * 3 + 1];   // y1 i1 x2 y2
    float4 c = pts[tid * 3 + 2];   // i2 x3 y3 i3

    float xs[4] = {a.x, a.w, b.z, c.y};
    float ys[4] = {a.y, b.x, b.w, c.z};
    float is[4] = {a.z, b.y, c.x, c.w};

    int tb0[4], sl0[4], tb1[4], sl1[4];
#pragma unroll
    for (int k = 0; k < 4; ++k) {
        float x = fminf(fmaxf(xs[k], 0.0f), (float)(W - 1));
        float y = fminf(fmaxf(ys[k], 0.0f), (float)(H - 1));
        xs[k] = x; ys[k] = y;
        int y0 = (int)floorf(y);
        int y1 = min(y0 + 1, H - 1);
        int t0 = y0 >> 3;                         // TROWS = 8
        int t1 = y1 >> 3;
        tb0[k] = t0;
        sl0[k] = (int)atomicAdd(&lcnt[t0], 1u);
        if (t1 != t0) {
            tb1[k] = t1;
            sl1[k] = (int)atomicAdd(&lcnt[t1], 1u);
        } else {
            tb1[k] = -1; sl1[k] = 0;
        }
    }
    __syncthreads();

    if (threadIdx.x < NTILES)
        lbase[threadIdx.x] = atomicAdd(&cnt[fb + threadIdx.x], lcnt[threadIdx.x]);
    __syncthreads();

#pragma unroll
    for (int k = 0; k < 4; ++k) {
        float4 rec = make_float4(xs[k], ys[k], is[k], 0.0f);
        unsigned s0 = lbase[tb0[k]] + (unsigned)sl0[k];
        if (s0 < (unsigned)CAP)
            buckets[(size_t)(fb + tb0[k]) * CAP + s0] = rec;
        if (tb1[k] >= 0) {
            unsigned s1 = lbase[tb1[k]] + (unsigned)sl1[k];
            if (s1 < (unsigned)CAP)
                buckets[(size_t)(fb + tb1[k]) * CAP + s1] = rec;
        }
    }
}

// ---------------------------------------------------------------------------
// Kernel 2: persistent block, 16 tiles, ASYNC double-buffered staging via
// global_load_lds with counted vmcnt (never drained mid-loop) + raw barriers.
// Per tile: zero acc | stage(next) | vmcnt(3)+bar | splat | bar | mse | bar.
// ---------------------------------------------------------------------------
__global__ void __launch_bounds__(512) k_tile(const float4* __restrict__ buckets,
                                              const unsigned int* __restrict__ cnt,
                                              const float* __restrict__ tgt,
                                              double* __restrict__ partials) {
    __shared__ __align__(16) float tileacc[TILE_WORDS];      // 16640 B
    __shared__ __align__(16) float tgtbufA[TROWS * W];       // 16384 B
    __shared__ __align__(16) float tgtbufB[TROWS * W];       // 16384 B
    __shared__ __align__(16) float4 bktbufA[CAP];            //  8192 B
    __shared__ __align__(16) float4 bktbufB[CAP];            //  8192 B
    __shared__ int ncache[TPB];
    __shared__ double sacc[8];

    int tid = threadIdx.x;
    int wv = tid >> 6, ln = tid & 63;
    int base = blockIdx.x * TPB;                 // 16 consecutive tiles, same frame
                                                 // (TPB divides NTILES)
    if (tid < TPB) ncache[tid] = (int)min(cnt[base + tid], (unsigned)CAP);

    // contiguous global sources for this block's 16 tiles
    const float4* tgt4 = (const float4*)(tgt + (size_t)(base >> 6) * HW +
                                         (size_t)(base & (NTILES - 1)) * TROWS * W);
    const float4* bkt0 = buckets + (size_t)base * CAP;

#define STAGE(j, tb_, bb_) do {                                                \
        const float4* ts_ = tgt4 + (j) * 1024;                                 \
        const float4* bs_ = bkt0 + (size_t)(j) * CAP;                          \
        int o_ = wv * 64 + ln;                                                 \
        gload16(ts_ + o_,       (char*)(tb_) + wv * 1024);                     \
        gload16(ts_ + 512 + o_, (char*)(tb_) + 8192 + wv * 1024);              \
        gload16(bs_ + o_,       (char*)(bb_) + wv * 1024);                     \
    } while (0)

    STAGE(0, tgtbufA, bktbufA);                  // prologue: tile 0 in flight

    double acc = 0.0;
    float4* t4 = (float4*)tileacc;

#pragma unroll
    for (int j = 0; j < TPB; ++j) {
        float*  tb  = (j & 1) ? tgtbufB : tgtbufA;
        float4* bb  = (j & 1) ? bktbufB : bktbufA;
        float*  tbn = (j & 1) ? tgtbufA : tgtbufB;
        float4* bbn = (j & 1) ? bktbufA : bktbufB;
        int r0 = ((base + j) & (NTILES - 1)) * TROWS;

        // ---- zero accumulator tile (1040 float4) ----
        float4 z = make_float4(0.f, 0.f, 0.f, 0.f);
        for (int i = tid; i < TILE_WORDS / 4; i += 512)
            t4[i] = z;

        // ---- issue NEXT tile's stage (stays in flight across barriers) ----
        if (j + 1 < TPB) STAGE(j + 1, tbn, bbn);

        // ---- wait for THIS tile's 3 stage ops only (leave next 3 flying) ----
        if (j + 1 < TPB) asm volatile("s_waitcnt vmcnt(3) lgkmcnt(0)" ::: "memory");
        else             asm volatile("s_waitcnt vmcnt(0) lgkmcnt(0)" ::: "memory");
        __builtin_amdgcn_sched_barrier(0);
        __builtin_amdgcn_s_barrier();

        // ---- splat from LDS bucket copy (<=1 point per thread) ----
        int n = ncache[j];
        if (tid < n) {
            float4 p = bb[tid];
            float x = p.x, y = p.y, inten = p.z;
            float x0f = floorf(x), y0f = floorf(y);
            float fx = x - x0f, fy = y - y0f;
            int x0 = (int)x0f, y0 = (int)y0f;
            int x1 = min(x0 + 1, W - 1);
            int y1 = min(y0 + 1, H - 1);
            int ra = y0 - r0;
            int rb = y1 - r0;
            float w00 = inten * (1.0f - fx) * (1.0f - fy);
            float w01 = inten * fx * (1.0f - fy);
            float w10 = inten * (1.0f - fx) * fy;
            float w11 = inten * fx * fy;
            if ((unsigned)ra < (unsigned)TROWS) {
                lds_add(&tileacc[ra * TPITCH + x0], w00);
                lds_add(&tileacc[ra * TPITCH + x1], w01);
            }
            if ((unsigned)rb < (unsigned)TROWS) {
                lds_add(&tileacc[rb * TPITCH + x0], w10);
                lds_add(&tileacc[rb * TPITCH + x1], w11);
            }
        }
        asm volatile("s_waitcnt lgkmcnt(0)" ::: "memory");
        __builtin_amdgcn_sched_barrier(0);
        __builtin_amdgcn_s_barrier();

        // ---- (img - tgt)^2 : 2 float4 (8 px) per thread, all from LDS ----
        float facc = 0.0f;
#pragma unroll
        for (int k = 0; k < 2; ++k) {
            int g4 = tid * 2 + k;                // 0..1023 float4 of the tile
            int r = g4 >> 7;                     // 128 float4 per row
            int c = (g4 & 127) << 2;
            float4 sv = *(const float4*)&tileacc[r * TPITCH + c];
            float4 tv = *(const float4*)&tb[g4 * 4];
            float d0 = sv.x - tv.x, d1 = sv.y - tv.y;
            float d2 = sv.z - tv.z, d3 = sv.w - tv.w;
            facc += d0 * d0 + d1 * d1 + d2 * d2 + d3 * d3;
        }
        acc += (double)facc;

        __builtin_amdgcn_s_barrier();            // protect tileacc/tb reuse
    }
#undef STAGE

    // ---- block reduction of f64 acc ----
    for (int off = 32; off > 0; off >>= 1)
        acc += __shfl_down(acc, off, 64);
    if (ln == 0) sacc[wv] = acc;
    __syncthreads();
    if (tid == 0) {
        double s = 0.0;
#pragma unroll
        for (int w2 = 0; w2 < 8; ++w2) s += sacc[w2];
        partials[blockIdx.x] = s;
    }
}

// ---------------------------------------------------------------------------
// Kernel 3: final reduce of TILE_BLOCKS partials -> mean -> d_out[0]
// ---------------------------------------------------------------------------
__global__ void __launch_bounds__(512) k_final(const double* __restrict__ partials,
                                               float* __restrict__ out) {
    double acc = 0.0;
    for (int i = threadIdx.x; i < TILE_BLOCKS; i += 512)
        acc += partials[i];
    for (int off = 32; off > 0; off >>= 1)
        acc += __shfl_down(acc, off, 64);
    __shared__ double sacc[8];
    int lane = threadIdx.x & 63;
    int wave = threadIdx.x >> 6;
    if (lane == 0) sacc[wave] = acc;
    __syncthreads();
    if (threadIdx.x == 0) {
        double s = 0.0;
#pragma unroll
        for (int wv = 0; wv < 8; ++wv) s += sacc[wv];
        out[0] = (float)(s / (double)TOT);
    }
}

// ---------------------------------------------------------------------------
extern "C" void kernel_launch(void* const* d_in, const int* in_sizes, int n_in,
                              void* d_out, int out_size, void* d_ws, size_t ws_size,
                              hipStream_t stream) {
    const float* pts = (const float*)d_in[0];     // [B, N, 3]
    const float* tgt = (const float*)d_in[1];     // [B, H, W]
    float* out = (float*)d_out;

    // ws layout: [ cnt 32KB | partials 4KB | pad to 128KB | buckets 64MiB ]
    unsigned int* cnt = (unsigned int*)d_ws;
    double* partials = (double*)((char*)d_ws + 32768);
    float4* buckets = (float4*)((char*)d_ws + 131072);

    k_zero<<<NBUCKETS / 512, 512, 0, stream>>>(cnt);
    k_bin<<<BIN_BLOCKS, 512, 0, stream>>>((const float4*)pts, buckets, cnt);
    k_tile<<<TILE_BLOCKS, 512, 0, stream>>>(buckets, cnt, tgt, partials);
    k_final<<<1, 512, 0, stream>>>(partials, out);
}